// Round 3
// baseline (877.447 us; speedup 1.0000x reference)
//
#include <hip/hip_runtime.h>
#include <math.h>
#include <stdint.h>

#define Bz 32
#define Sz 2048
#define Dz 1024
#define Uz 1024
#define Mz (Bz*Sz)

typedef __attribute__((ext_vector_type(8))) short bf16x8;
typedef __attribute__((ext_vector_type(4))) float f32x4;

__device__ __forceinline__ unsigned short f2bf(float f) {
    union { float f; uint32_t u; } v; v.f = f;
    uint32_t r = v.u + 0x7FFFu + ((v.u >> 16) & 1u);   // RNE
    return (unsigned short)(r >> 16);
}

__device__ __forceinline__ float fast_tanh(float x) {
    float e = __expf(2.f * x);
    return 1.f - 2.f * __builtin_amdgcn_rcpf(e + 1.f);
}

#define GLD16(gsrc, ldst) \
    __builtin_amdgcn_global_load_lds((__attribute__((address_space(1))) void*)(void*)(gsrc), \
        (__attribute__((address_space(3))) void*)(ldst), 16, 0, 0)

#define CONV_BLOCKS 16384   // (Mz*Dz)/(256*16)
#define WT_BLOCKS   256
#define DECI_BLOCKS 32
#define SINIT_BLOCKS 64     // Bz*Sz / (256*4)

// ---------------------------------------------------------------------------
// PREP (fused): h_enc->bf16 | W_enc->wT bf16 | dec_p = b_dec | score = b_com
// ---------------------------------------------------------------------------
__global__ __launch_bounds__(256) void prep_kernel(
    const float* __restrict__ h_enc, unsigned short* __restrict__ hbf,
    const float* __restrict__ W_enc, unsigned short* __restrict__ wT,
    const float* __restrict__ b_dec, float* __restrict__ dec_p,
    const float* __restrict__ b_com, float* __restrict__ score)
{
    __shared__ float tile[64][65];
    const int bid = blockIdx.x;
    const int tid = threadIdx.x;
    if (bid < CONV_BLOCKS) {
        const size_t i = ((size_t)bid * 256 + tid) * 16;
#pragma unroll
        for (int h = 0; h < 2; ++h) {
            const float4 a = *(const float4*)(h_enc + i + h * 8);
            const float4 c = *(const float4*)(h_enc + i + h * 8 + 4);
            union { unsigned short s[8]; uint4 v; } o;
            o.s[0] = f2bf(a.x); o.s[1] = f2bf(a.y); o.s[2] = f2bf(a.z); o.s[3] = f2bf(a.w);
            o.s[4] = f2bf(c.x); o.s[5] = f2bf(c.y); o.s[6] = f2bf(c.z); o.s[7] = f2bf(c.w);
            *(uint4*)(hbf + i + h * 8) = o.v;
        }
    } else if (bid < CONV_BLOCKS + WT_BLOCKS) {
        const int b2 = bid - CONV_BLOCKS;
        const int c  = tid & 63;
        const int r0 = tid >> 6;
        const int u0 = (b2 & 15) * 64;
        const int d0 = (b2 >> 4) * 64;
        for (int r = r0; r < 64; r += 4)
            tile[r][c] = W_enc[(size_t)(d0 + r) * Uz + u0 + c];
        __syncthreads();
        for (int r = r0; r < 64; r += 4)
            wT[(size_t)(u0 + r) * Dz + d0 + c] = f2bf(tile[c][r]);
    } else if (bid < CONV_BLOCKS + WT_BLOCKS + DECI_BLOCKS) {
        const int b3 = bid - (CONV_BLOCKS + WT_BLOCKS);
        const int u4 = tid * 4;
        *(float4*)&dec_p[b3 * Uz + u4] = *(const float4*)&b_dec[u4];
    } else {
        const int b4 = bid - (CONV_BLOCKS + WT_BLOCKS + DECI_BLOCKS);
        const float bc = b_com[0];
        const int i4 = (b4 * 256 + tid) * 4;
        float4 v = {bc, bc, bc, bc};
        *(float4*)&score[i4] = v;
    }
}

// ---------------------------------------------------------------------------
// dec_p[b,u] += partial h_dec[b,:]@W_dec (8 d-chunks, atop b_dec init)
// ---------------------------------------------------------------------------
__global__ __launch_bounds__(256) void dec_partial_kernel(
    const float* __restrict__ h_dec, const float* __restrict__ W_dec,
    float* __restrict__ dec_p)
{
    __shared__ float hs[128];
    const int b  = blockIdx.x >> 3;
    const int d0 = (blockIdx.x & 7) * 128;
    const int tid = threadIdx.x;
    const int u4 = tid * 4;
    if (tid < 128) hs[tid] = h_dec[b * Dz + d0 + tid];
    __syncthreads();
    float4 acc = {0.f, 0.f, 0.f, 0.f};
#pragma unroll 4
    for (int d = 0; d < 128; ++d) {
        const float  a = hs[d];
        const float4 w = *(const float4*)&W_dec[(size_t)(d0 + d) * Uz + u4];
        acc.x += a * w.x; acc.y += a * w.y; acc.z += a * w.z; acc.w += a * w.w;
    }
    float* o = dec_p + b * Uz + u4;
    atomicAdd(o + 0, acc.x); atomicAdd(o + 1, acc.y);
    atomicAdd(o + 2, acc.z); atomicAdd(o + 3, acc.w);
}

// ---------------------------------------------------------------------------
// K2 (hot, MFMA): v4 — 128x128 tile, BK=64 (was 32). Round-2 showed the
// 2-barrier step is LATENCY-bound (MfmaUtil 17%, VALU 14%, HBM 4.5%):
// time ~ K-step count x serial step cost. BK=64 halves the step count,
// doubling MFMA (16->32/wave) and GLD16 (4->8/wave) per vmcnt(0)+barrier
// pair. LDS 32KB, ~4 blocks/CU retained for cross-block latency hiding.
// XCD-chunked swizzle + fetch-once A-tiles kept from round 2 (FETCH 102MB).
// Fragment-linear LDS: unit = (g-group, k-half), 1KB each, conflict-free.
// ---------------------------------------------------------------------------
__global__ __launch_bounds__(256) void score_mfma_kernel(
    const unsigned short* __restrict__ hbf,   // [Mz][Dz] bf16
    const unsigned short* __restrict__ wT,    // [Uz][Dz] bf16
    const float* __restrict__ dec_p,
    const float* __restrict__ W_com,
    float* __restrict__ score)
{
    __shared__ unsigned short As[16 * 512];   // (g 0..7) x (kh 0..1) x 64 lanes x 8 bf16
    __shared__ unsigned short Bs[16 * 512];

    const int tid  = threadIdx.x;
    const int w    = tid >> 6;
    const int lane = tid & 63;
    const int ln   = lane & 15;
    const int q    = lane >> 4;
    const int wm   = w & 1;
    const int wn   = w >> 1;

    // XCD-chunked swizzle (bijective: 8*64*8 = 4096 = grid)
    const int xcd = blockIdx.x & 7;
    const int idx = blockIdx.x >> 3;
    const int mb  = xcd * 64 + (idx >> 3);   // [0,512)
    const int m0  = mb * 128;
    const int ub  = (idx & 7) * 128;         // u-block [0,1024) step 128
    const int b   = m0 / Sz;

    // staging: wave w owns m/n-groups 2w and 2w+1, both k-halves
    const unsigned short* a_src0 = hbf + (size_t)(m0 + (2 * w) * 16 + ln) * Dz + q * 8;
    const unsigned short* a_src1 = a_src0 + (size_t)16 * Dz;
    const unsigned short* b_src0 = wT + (size_t)(ub + (2 * w) * 16 + ln) * Dz + q * 8;
    const unsigned short* b_src1 = b_src0 + (size_t)16 * Dz;
    unsigned short* a_dst0 = As + (4 * w) * 512;        // g=2w,   kh=0/1 at +0/+512
    unsigned short* a_dst1 = As + (4 * w + 2) * 512;    // g=2w+1, kh=0/1
    unsigned short* b_dst0 = Bs + (4 * w) * 512;
    unsigned short* b_dst1 = Bs + (4 * w + 2) * 512;

    f32x4 acc[4][4];
#pragma unroll
    for (int i = 0; i < 4; ++i)
#pragma unroll
        for (int j = 0; j < 4; ++j) acc[i][j] = (f32x4){0.f, 0.f, 0.f, 0.f};

    for (int k0 = 0; k0 < Dz; k0 += 64) {
        __syncthreads();                  // protect LDS from prev readers
        GLD16(a_src0 + k0,      a_dst0);
        GLD16(a_src0 + k0 + 32, a_dst0 + 512);
        GLD16(a_src1 + k0,      a_dst1);
        GLD16(a_src1 + k0 + 32, a_dst1 + 512);
        GLD16(b_src0 + k0,      b_dst0);
        GLD16(b_src0 + k0 + 32, b_dst0 + 512);
        GLD16(b_src1 + k0,      b_dst1);
        GLD16(b_src1 + k0 + 32, b_dst1 + 512);
        __syncthreads();                  // vmcnt drained before barrier

#pragma unroll
        for (int kh = 0; kh < 2; ++kh) {
            bf16x8 af[4], bfr[4];
#pragma unroll
            for (int i = 0; i < 4; ++i)
                af[i] = *(const bf16x8*)(As + ((wm * 4 + i) * 2 + kh) * 512 + lane * 8);
#pragma unroll
            for (int j = 0; j < 4; ++j)
                bfr[j] = *(const bf16x8*)(Bs + ((wn * 4 + j) * 2 + kh) * 512 + lane * 8);
#pragma unroll
            for (int i = 0; i < 4; ++i)
#pragma unroll
                for (int j = 0; j < 4; ++j)
                    acc[i][j] = __builtin_amdgcn_mfma_f32_16x16x32_bf16(
                        af[i], bfr[j], acc[i][j], 0, 0, 0);
        }
    }

    // epilogue (once per block): tanh + dot(W_com), 16-lane reduce, atomicAdd
    float dpv[4], wcv[4];
#pragma unroll
    for (int j = 0; j < 4; ++j) {
        const int u = ub + (wn * 4 + j) * 16 + ln;
        dpv[j] = dec_p[b * Uz + u];
        wcv[j] = W_com[u];
    }
    float racc[4][4];
#pragma unroll
    for (int i = 0; i < 4; ++i)
#pragma unroll
        for (int r = 0; r < 4; ++r) {
            float v = 0.f;
#pragma unroll
            for (int j = 0; j < 4; ++j)
                v += fast_tanh(acc[i][j][r] + dpv[j]) * wcv[j];
            racc[i][r] = v;
        }

#pragma unroll
    for (int off = 1; off < 16; off <<= 1)
#pragma unroll
        for (int i = 0; i < 4; ++i)
#pragma unroll
            for (int r = 0; r < 4; ++r)
                racc[i][r] += __shfl_xor(racc[i][r], off, 64);
    if (ln == 0) {
#pragma unroll
        for (int i = 0; i < 4; ++i)
#pragma unroll
            for (int r = 0; r < 4; ++r)
                atomicAdd(&score[m0 + wm * 64 + i * 16 + q * 4 + r], racc[i][r]);
    }
}

// ---------------------------------------------------------------------------
// softmax (blocks 0..31) + out_ctx init = b_enc (32..63)
// ---------------------------------------------------------------------------
__global__ __launch_bounds__(256) void softmax_init_kernel(
    const float* __restrict__ score, float* __restrict__ attn,
    const float* __restrict__ b_enc, float* __restrict__ out_ctx)
{
    __shared__ float red[256];
    const int tid = threadIdx.x;
    if (blockIdx.x >= Bz) {
        const int b2 = blockIdx.x - Bz;
        const int u4 = tid * 4;
        *(float4*)&out_ctx[b2 * Uz + u4] = *(const float4*)&b_enc[u4];
        return;
    }
    const int b = blockIdx.x;
    const float* srow = score + b * Sz;
    float v[8];
    float lm = -1e30f;
#pragma unroll
    for (int i = 0; i < 8; ++i) { v[i] = srow[i * 256 + tid]; lm = fmaxf(lm, v[i]); }
    red[tid] = lm; __syncthreads();
    for (int off = 128; off > 0; off >>= 1) {
        if (tid < off) red[tid] = fmaxf(red[tid], red[tid + off]);
        __syncthreads();
    }
    const float mx = red[0];
    __syncthreads();
    float ls = 0.f;
#pragma unroll
    for (int i = 0; i < 8; ++i) { v[i] = expf(v[i] - mx); ls += v[i]; }
    red[tid] = ls; __syncthreads();
    for (int off = 128; off > 0; off >>= 1) {
        if (tid < off) red[tid] += red[tid + off];
        __syncthreads();
    }
    const float inv = 1.f / red[0];
#pragma unroll
    for (int i = 0; i < 8; ++i) attn[b * Sz + i * 256 + tid] = v[i] * inv;
}

// ---------------------------------------------------------------------------
// wsum[b,d] = sum_s attn[b,s]*h_enc[b,s,d] — v2: atomic-free. Grid Bz*8;
// block owns (b, 128 d-cols); threads split s in two halves, LDS-reduce.
// Removes 1M device-scope atomicAdds + the wsum zero-init pass.
// ---------------------------------------------------------------------------
__global__ __launch_bounds__(256) void wsum_kernel(
    const float* __restrict__ h_enc, const float* __restrict__ attn,
    float* __restrict__ wsum)
{
    __shared__ float aw[Sz];      // 8 KB: whole attn row
    __shared__ float red[256];
    const int b    = blockIdx.x >> 3;
    const int d0   = (blockIdx.x & 7) * 128;
    const int tid  = threadIdx.x;
    const int half = tid >> 7;            // s-half
    const int dl   = tid & 127;
    const int d    = d0 + dl;

    for (int i = tid; i < Sz; i += 256) aw[i] = attn[b * Sz + i];
    __syncthreads();

    const float* base = h_enc + ((size_t)b * Sz + half * 1024) * Dz + d;
    float acc = 0.f;
#pragma unroll 4
    for (int s = 0; s < 1024; ++s)
        acc += aw[half * 1024 + s] * base[(size_t)s * Dz];
    red[tid] = acc;
    __syncthreads();
    if (tid < 128)
        wsum[b * Dz + d] = red[tid] + red[tid + 128];
}

// ---------------------------------------------------------------------------
// out_ctx[b,u] += partial wsum[b,:]@W_enc (8 d-chunks, atop b_enc init)
// ---------------------------------------------------------------------------
__global__ __launch_bounds__(256) void ctx_partial_kernel(
    const float* __restrict__ wsum, const float* __restrict__ W_enc,
    float* __restrict__ out_ctx)
{
    __shared__ float hs[128];
    const int b  = blockIdx.x >> 3;
    const int d0 = (blockIdx.x & 7) * 128;
    const int tid = threadIdx.x;
    const int u4 = tid * 4;
    if (tid < 128) hs[tid] = wsum[b * Dz + d0 + tid];
    __syncthreads();
    float4 acc = {0.f, 0.f, 0.f, 0.f};
#pragma unroll 4
    for (int d = 0; d < 128; ++d) {
        const float  a = hs[d];
        const float4 wv = *(const float4*)&W_enc[(size_t)(d0 + d) * Uz + u4];
        acc.x += a * wv.x; acc.y += a * wv.y; acc.z += a * wv.z; acc.w += a * wv.w;
    }
    float* o = out_ctx + b * Uz + u4;
    atomicAdd(o + 0, acc.x); atomicAdd(o + 1, acc.y);
    atomicAdd(o + 2, acc.z); atomicAdd(o + 3, acc.w);
}

// ---------------------------------------------------------------------------
// Fallback fp32 path (only if ws too small for bf16 staging)
// ---------------------------------------------------------------------------
__global__ __launch_bounds__(256) void dec_proj_kernel(
    const float* __restrict__ h_dec, const float* __restrict__ W_dec,
    const float* __restrict__ b_dec, float* __restrict__ dec_p)
{
    __shared__ float hs[Dz];
    const int b = blockIdx.x >> 2;
    const int u = ((blockIdx.x & 3) << 8) + threadIdx.x;
    for (int d = threadIdx.x; d < Dz; d += 256) hs[d] = h_dec[b * Dz + d];
    __syncthreads();
    float acc = 0.f;
#pragma unroll 4
    for (int d = 0; d < Dz; ++d) acc += hs[d] * W_dec[d * Uz + u];
    dec_p[b * Uz + u] = acc + b_dec[u];
}

#define MT 64
#define NT 64
#define KT 64
__global__ __launch_bounds__(256) void score_kernel(
    const float* __restrict__ h_enc, const float* __restrict__ W_enc,
    const float* __restrict__ dec_p, const float* __restrict__ W_com,
    const float* __restrict__ b_com, float* __restrict__ score)
{
    __shared__ __align__(16) float As[KT][MT + 4];
    __shared__ __align__(16) float Bs[KT][NT + 4];
    __shared__ float red[MT][17];
    const int tid = threadIdx.x;
    const int tx = tid & 15;
    const int ty = tid >> 4;
    const int m0 = blockIdx.x * MT;
    const int b  = m0 / Sz;
    float s_acc = 0.f;
    for (int u0 = 0; u0 < Uz; u0 += NT) {
        float acc[4][4];
#pragma unroll
        for (int i = 0; i < 4; ++i)
#pragma unroll
            for (int j = 0; j < 4; ++j) acc[i][j] = 0.f;
        for (int k0 = 0; k0 < Dz; k0 += KT) {
            __syncthreads();
#pragma unroll
            for (int i = 0; i < 4; ++i) {
                const int row = ty + i * 16;
                const int c4  = tx * 4;
                const float4 v = *(const float4*)&h_enc[(size_t)(m0 + row) * Dz + k0 + c4];
                As[c4 + 0][row] = v.x; As[c4 + 1][row] = v.y;
                As[c4 + 2][row] = v.z; As[c4 + 3][row] = v.w;
            }
#pragma unroll
            for (int i = 0; i < 4; ++i) {
                const int row = ty + i * 16;
                *(float4*)&Bs[row][tx * 4] =
                    *(const float4*)&W_enc[(size_t)(k0 + row) * Uz + u0 + tx * 4];
            }
            __syncthreads();
#pragma unroll 8
            for (int k = 0; k < KT; ++k) {
                const float4 a = *(const float4*)&As[k][ty * 4];
                const float4 wv = *(const float4*)&Bs[k][tx * 4];
                acc[0][0] += a.x * wv.x; acc[0][1] += a.x * wv.y; acc[0][2] += a.x * wv.z; acc[0][3] += a.x * wv.w;
                acc[1][0] += a.y * wv.x; acc[1][1] += a.y * wv.y; acc[1][2] += a.y * wv.z; acc[1][3] += a.y * wv.w;
                acc[2][0] += a.z * wv.x; acc[2][1] += a.z * wv.y; acc[2][2] += a.z * wv.z; acc[2][3] += a.z * wv.w;
                acc[3][0] += a.w * wv.x; acc[3][1] += a.w * wv.y; acc[3][2] += a.w * wv.z; acc[3][3] += a.w * wv.w;
            }
        }
        const float4 dp = *(const float4*)&dec_p[b * Uz + u0 + tx * 4];
        const float4 wc = *(const float4*)&W_com[u0 + tx * 4];
#pragma unroll
        for (int i = 0; i < 4; ++i) {
            const float p = tanhf(acc[i][0] + dp.x) * wc.x + tanhf(acc[i][1] + dp.y) * wc.y
                          + tanhf(acc[i][2] + dp.z) * wc.z + tanhf(acc[i][3] + dp.w) * wc.w;
            red[ty * 4 + i][tx] = p;
        }
        __syncthreads();
        if (tid < MT) {
            float t = 0.f;
#pragma unroll
            for (int j = 0; j < 16; ++j) t += red[tid][j];
            s_acc += t;
        }
    }
    if (tid < MT) score[m0 + tid] = s_acc + b_com[0];
}

__global__ __launch_bounds__(256) void ctx_kernel(
    const float* __restrict__ wsum, const float* __restrict__ W_enc,
    const float* __restrict__ b_enc, float* __restrict__ out)
{
    __shared__ float hs[Dz];
    const int b = blockIdx.x >> 2;
    const int u = ((blockIdx.x & 3) << 8) + threadIdx.x;
    for (int d = threadIdx.x; d < Dz; d += 256) hs[d] = wsum[b * Dz + d];
    __syncthreads();
    float acc = 0.f;
#pragma unroll 4
    for (int d = 0; d < Dz; ++d) acc += hs[d] * W_enc[d * Uz + u];
    out[b * Uz + u] = acc + b_enc[u];
}

// ---------------------------------------------------------------------------
extern "C" void kernel_launch(void* const* d_in, const int* in_sizes, int n_in,
                              void* d_out, int out_size, void* d_ws, size_t ws_size,
                              hipStream_t stream)
{
    const float* h_enc = (const float*)d_in[0];
    const float* h_dec = (const float*)d_in[1];
    const float* W_enc = (const float*)d_in[2];
    const float* b_enc = (const float*)d_in[3];
    const float* W_dec = (const float*)d_in[4];
    const float* b_dec = (const float*)d_in[5];
    const float* W_com = (const float*)d_in[6];
    const float* b_com = (const float*)d_in[7];

    float* out_ctx  = (float*)d_out;            // [B,U]
    float* out_attn = out_ctx + Bz * Uz;        // [B,S]

    const size_t HBF_BYTES = (size_t)Mz * Dz * 2;       // 128 MiB
    const size_t WT_BYTES  = (size_t)Uz * Dz * 2;       // 2 MiB
    const size_t SMALL     = (size_t)(Bz*Uz + Bz*Sz + Bz*Dz) * 4;
    const size_t need      = HBF_BYTES + WT_BYTES + SMALL;

    if (ws_size >= need) {
        char* wsb = (char*)d_ws;
        unsigned short* hbf = (unsigned short*)wsb;
        unsigned short* wT  = (unsigned short*)(wsb + HBF_BYTES);
        float* dec_p = (float*)(wsb + HBF_BYTES + WT_BYTES);
        float* score = dec_p + Bz * Uz;
        float* wsum  = score + Bz * Sz;

        prep_kernel<<<CONV_BLOCKS + WT_BLOCKS + DECI_BLOCKS + SINIT_BLOCKS, 256, 0, stream>>>(
            h_enc, hbf, W_enc, wT, b_dec, dec_p, b_com, score);
        dec_partial_kernel<<<Bz * 8, 256, 0, stream>>>(h_dec, W_dec, dec_p);
        score_mfma_kernel<<<(Mz / 128) * (Uz / 128), 256, 0, stream>>>(hbf, wT, dec_p, W_com, score);
        softmax_init_kernel<<<2 * Bz, 256, 0, stream>>>(score, out_attn, b_enc, out_ctx);
        wsum_kernel<<<Bz * 8, 256, 0, stream>>>(h_enc, out_attn, wsum);
        ctx_partial_kernel<<<Bz * 8, 256, 0, stream>>>(wsum, W_enc, out_ctx);
    } else {
        float* ws    = (float*)d_ws;
        float* dec_p = ws;
        float* score = ws + Bz * Uz;
        float* wsum  = ws + Bz * Uz + Bz * Sz;

        dec_proj_kernel<<<(Bz * Uz) / 256, 256, 0, stream>>>(h_dec, W_dec, b_dec, dec_p);
        score_kernel<<<Mz / MT, 256, 0, stream>>>(h_enc, W_enc, dec_p, W_com, b_com, score);
        softmax_init_kernel<<<2 * Bz, 256, 0, stream>>>(score, out_attn, b_enc, out_ctx);
        wsum_kernel<<<Bz * 8, 256, 0, stream>>>(h_enc, out_attn, wsum);
        ctx_kernel<<<(Bz * Uz) / 256, 256, 0, stream>>>(wsum, W_enc, b_enc, out_ctx);
    }
}

// Round 4
// 705.121 us; speedup vs baseline: 1.2444x; 1.2444x over previous
//
#include <hip/hip_runtime.h>
#include <math.h>
#include <stdint.h>

#define Bz 32
#define Sz 2048
#define Dz 1024
#define Uz 1024
#define Mz (Bz*Sz)

typedef __attribute__((ext_vector_type(8))) short bf16x8;
typedef __attribute__((ext_vector_type(4))) float f32x4;

__device__ __forceinline__ unsigned short f2bf(float f) {
    union { float f; uint32_t u; } v; v.f = f;
    uint32_t r = v.u + 0x7FFFu + ((v.u >> 16) & 1u);   // RNE
    return (unsigned short)(r >> 16);
}

__device__ __forceinline__ float fast_tanh(float x) {
    float e = __expf(2.f * x);
    return 1.f - 2.f * __builtin_amdgcn_rcpf(e + 1.f);
}

#define GLD16(gsrc, ldst) \
    __builtin_amdgcn_global_load_lds((__attribute__((address_space(1))) void*)(void*)(gsrc), \
        (__attribute__((address_space(3))) void*)(ldst), 16, 0, 0)

#define CONV_BLOCKS 16384   // (Mz*Dz)/(256*16)
#define WT_BLOCKS   256
#define DECI_BLOCKS 32
#define SINIT_BLOCKS 64     // Bz*Sz / (256*4)

// ---------------------------------------------------------------------------
// PREP (fused): h_enc->bf16 | W_enc->wT bf16 | dec_p = b_dec | score = b_com
// ---------------------------------------------------------------------------
__global__ __launch_bounds__(256) void prep_kernel(
    const float* __restrict__ h_enc, unsigned short* __restrict__ hbf,
    const float* __restrict__ W_enc, unsigned short* __restrict__ wT,
    const float* __restrict__ b_dec, float* __restrict__ dec_p,
    const float* __restrict__ b_com, float* __restrict__ score)
{
    __shared__ float tile[64][65];
    const int bid = blockIdx.x;
    const int tid = threadIdx.x;
    if (bid < CONV_BLOCKS) {
        const size_t i = ((size_t)bid * 256 + tid) * 16;
#pragma unroll
        for (int h = 0; h < 2; ++h) {
            const float4 a = *(const float4*)(h_enc + i + h * 8);
            const float4 c = *(const float4*)(h_enc + i + h * 8 + 4);
            union { unsigned short s[8]; uint4 v; } o;
            o.s[0] = f2bf(a.x); o.s[1] = f2bf(a.y); o.s[2] = f2bf(a.z); o.s[3] = f2bf(a.w);
            o.s[4] = f2bf(c.x); o.s[5] = f2bf(c.y); o.s[6] = f2bf(c.z); o.s[7] = f2bf(c.w);
            *(uint4*)(hbf + i + h * 8) = o.v;
        }
    } else if (bid < CONV_BLOCKS + WT_BLOCKS) {
        const int b2 = bid - CONV_BLOCKS;
        const int c  = tid & 63;
        const int r0 = tid >> 6;
        const int u0 = (b2 & 15) * 64;
        const int d0 = (b2 >> 4) * 64;
        for (int r = r0; r < 64; r += 4)
            tile[r][c] = W_enc[(size_t)(d0 + r) * Uz + u0 + c];
        __syncthreads();
        for (int r = r0; r < 64; r += 4)
            wT[(size_t)(u0 + r) * Dz + d0 + c] = f2bf(tile[c][r]);
    } else if (bid < CONV_BLOCKS + WT_BLOCKS + DECI_BLOCKS) {
        const int b3 = bid - (CONV_BLOCKS + WT_BLOCKS);
        const int u4 = tid * 4;
        *(float4*)&dec_p[b3 * Uz + u4] = *(const float4*)&b_dec[u4];
    } else {
        const int b4 = bid - (CONV_BLOCKS + WT_BLOCKS + DECI_BLOCKS);
        const float bc = b_com[0];
        const int i4 = (b4 * 256 + tid) * 4;
        float4 v = {bc, bc, bc, bc};
        *(float4*)&score[i4] = v;
    }
}

// ---------------------------------------------------------------------------
// dec_p[b,u] += partial h_dec[b,:]@W_dec (8 d-chunks, atop b_dec init)
// ---------------------------------------------------------------------------
__global__ __launch_bounds__(256) void dec_partial_kernel(
    const float* __restrict__ h_dec, const float* __restrict__ W_dec,
    float* __restrict__ dec_p)
{
    __shared__ float hs[128];
    const int b  = blockIdx.x >> 3;
    const int d0 = (blockIdx.x & 7) * 128;
    const int tid = threadIdx.x;
    const int u4 = tid * 4;
    if (tid < 128) hs[tid] = h_dec[b * Dz + d0 + tid];
    __syncthreads();
    float4 acc = {0.f, 0.f, 0.f, 0.f};
#pragma unroll 4
    for (int d = 0; d < 128; ++d) {
        const float  a = hs[d];
        const float4 w = *(const float4*)&W_dec[(size_t)(d0 + d) * Uz + u4];
        acc.x += a * w.x; acc.y += a * w.y; acc.z += a * w.z; acc.w += a * w.w;
    }
    float* o = dec_p + b * Uz + u4;
    atomicAdd(o + 0, acc.x); atomicAdd(o + 1, acc.y);
    atomicAdd(o + 2, acc.z); atomicAdd(o + 3, acc.w);
}

// ---------------------------------------------------------------------------
// K2 (hot, MFMA) v5: 256x256 tile, 8 waves (512 thr), BK=64, 2-phase dbuf.
// Rationale: rounds 0-3 showed the per-K-step serial cost (stage+vmcnt(0)+
// barrier) dominates regardless of BK/grid/traffic. 2-phase prefetch only
// pays when compute-per-step covers load latency: at 256^2/8-wave each step
// has 64 MFMA/wave (~2500cy matrix work per CU) >> ~500cy latency. Catalog
// m248v2 (2ph, 256^2, K=1024, gload_lds) = 666 TF vs our 411.
// Wave grid 2Mx4N, per-wave output 128x64 (acc[8][4] f32x4 = 128 VGPR).
// Fragment-linear LDS units (1KB = 64 lanes x 16B), GLD16 direct, 0 bank
// conflicts. LDS 2x(32+32)KB + 4KB sred = 132KB -> 1 block/CU.
// In-block LDS reduction of score partials: 256 atomics/block (was 1024).
// ---------------------------------------------------------------------------
__global__ __launch_bounds__(512, 2) void score_mfma_kernel(
    const unsigned short* __restrict__ hbf,   // [Mz][Dz] bf16
    const unsigned short* __restrict__ wT,    // [Uz][Dz] bf16
    const float* __restrict__ dec_p,
    const float* __restrict__ W_com,
    float* __restrict__ score)
{
    __shared__ unsigned short As[2][32 * 512];   // 32 units x (64 lanes x 8 bf16)
    __shared__ unsigned short Bs[2][32 * 512];
    __shared__ float sred[4][256];

    const int tid  = threadIdx.x;
    const int w    = tid >> 6;        // 0..7
    const int lane = tid & 63;
    const int ln   = lane & 15;
    const int q    = lane >> 4;
    const int wm   = w >> 2;          // 0..1  (m-half)
    const int wn   = w & 3;           // 0..3  (n-quarter)

    // XCD-chunked swizzle (bijective: grid 1024 = 8 xcd x 32 mb x 4 ub)
    const int xcd = blockIdx.x & 7;
    const int idx = blockIdx.x >> 3;          // 0..127
    const int mb  = xcd * 32 + (idx >> 2);    // 0..255
    const int m0  = mb * 256;
    const int ub  = (idx & 3) * 256;
    const int b   = m0 / Sz;

    // staging sources: wave w owns A units 4w..4w+3 (g=2w,2w+1 x kh=0,1), same for B
    const unsigned short* aA0 = hbf + (size_t)(m0 + w * 32 + ln) * Dz + q * 8;
    const unsigned short* aA1 = aA0 + (size_t)16 * Dz;
    const unsigned short* bB0 = wT + (size_t)(ub + w * 32 + ln) * Dz + q * 8;
    const unsigned short* bB1 = bB0 + (size_t)16 * Dz;

#define STAGE(nb_, k0_) do { \
        unsigned short* ad = &As[nb_][(w * 4) * 512]; \
        unsigned short* bd = &Bs[nb_][(w * 4) * 512]; \
        GLD16(aA0 + (k0_),      ad); \
        GLD16(aA0 + (k0_) + 32, ad + 512); \
        GLD16(aA1 + (k0_),      ad + 1024); \
        GLD16(aA1 + (k0_) + 32, ad + 1536); \
        GLD16(bB0 + (k0_),      bd); \
        GLD16(bB0 + (k0_) + 32, bd + 512); \
        GLD16(bB1 + (k0_),      bd + 1024); \
        GLD16(bB1 + (k0_) + 32, bd + 1536); \
    } while (0)

    f32x4 acc[8][4];
#pragma unroll
    for (int i = 0; i < 8; ++i)
#pragma unroll
        for (int j = 0; j < 4; ++j) acc[i][j] = (f32x4){0.f, 0.f, 0.f, 0.f};

#define COMPUTE(cb_) do { \
        _Pragma("unroll") \
        for (int kh = 0; kh < 2; ++kh) { \
            bf16x8 af[8], bfr[4]; \
            _Pragma("unroll") \
            for (int i = 0; i < 8; ++i) \
                af[i] = *(const bf16x8*)(&As[cb_][(((wm * 8 + i) << 1) + kh) * 512 + lane * 8]); \
            _Pragma("unroll") \
            for (int j = 0; j < 4; ++j) \
                bfr[j] = *(const bf16x8*)(&Bs[cb_][(((wn * 4 + j) << 1) + kh) * 512 + lane * 8]); \
            _Pragma("unroll") \
            for (int i = 0; i < 8; ++i) \
                _Pragma("unroll") \
                for (int j = 0; j < 4; ++j) \
                    acc[i][j] = __builtin_amdgcn_mfma_f32_16x16x32_bf16( \
                        af[i], bfr[j], acc[i][j], 0, 0, 0); \
        } \
    } while (0)

    // prologue: fill buffer 0 with K-step 0
    STAGE(0, 0);
    __syncthreads();

    int nb = 0;
    for (int t = 0; t < 15; ++t) {
        STAGE(nb ^ 1, (t + 1) * 64);   // prefetch next K-step
        COMPUTE(nb);                   // 64 MFMA/wave on current
        __syncthreads();               // vmcnt(0)+drain lands after compute
        nb ^= 1;
    }
    COMPUTE(nb);                       // last K-step, no prefetch

    // epilogue: tanh + dot(W_com); reduce over ln-lanes; in-block LDS reduce
    float dpv[4], wcv[4];
#pragma unroll
    for (int j = 0; j < 4; ++j) {
        const int u = ub + wn * 64 + j * 16 + ln;
        dpv[j] = dec_p[b * Uz + u];
        wcv[j] = W_com[u];
    }
    float racc[8][4];
#pragma unroll
    for (int i = 0; i < 8; ++i)
#pragma unroll
        for (int r = 0; r < 4; ++r) {
            float v = 0.f;
#pragma unroll
            for (int j = 0; j < 4; ++j)
                v += fast_tanh(acc[i][j][r] + dpv[j]) * wcv[j];
            racc[i][r] = v;
        }
#pragma unroll
    for (int off = 1; off < 16; off <<= 1)
#pragma unroll
        for (int i = 0; i < 8; ++i)
#pragma unroll
            for (int r = 0; r < 4; ++r)
                racc[i][r] += __shfl_xor(racc[i][r], off, 64);
    if (ln == 0) {
#pragma unroll
        for (int i = 0; i < 8; ++i)
#pragma unroll
            for (int r = 0; r < 4; ++r)
                sred[wn][wm * 128 + i * 16 + q * 4 + r] = racc[i][r];
    }
    __syncthreads();
    if (tid < 256) {
        const float s = sred[0][tid] + sred[1][tid] + sred[2][tid] + sred[3][tid];
        atomicAdd(&score[m0 + tid], s);
    }
#undef STAGE
#undef COMPUTE
}

// ---------------------------------------------------------------------------
// softmax (blocks 0..31) + out_ctx init = b_enc (32..63) + wsum zero (64..95)
// ---------------------------------------------------------------------------
__global__ __launch_bounds__(256) void softmax_init_kernel(
    const float* __restrict__ score, float* __restrict__ attn,
    const float* __restrict__ b_enc, float* __restrict__ out_ctx,
    float* __restrict__ wsum)
{
    __shared__ float red[256];
    const int tid = threadIdx.x;
    if (blockIdx.x >= 2 * Bz) {
        const int b3 = blockIdx.x - 2 * Bz;
        float4 z = {0.f, 0.f, 0.f, 0.f};
        *(float4*)&wsum[b3 * Dz + tid * 4] = z;
        return;
    }
    if (blockIdx.x >= Bz) {
        const int b2 = blockIdx.x - Bz;
        const int u4 = tid * 4;
        *(float4*)&out_ctx[b2 * Uz + u4] = *(const float4*)&b_enc[u4];
        return;
    }
    const int b = blockIdx.x;
    const float* srow = score + b * Sz;
    float v[8];
    float lm = -1e30f;
#pragma unroll
    for (int i = 0; i < 8; ++i) { v[i] = srow[i * 256 + tid]; lm = fmaxf(lm, v[i]); }
    red[tid] = lm; __syncthreads();
    for (int off = 128; off > 0; off >>= 1) {
        if (tid < off) red[tid] = fmaxf(red[tid], red[tid + off]);
        __syncthreads();
    }
    const float mx = red[0];
    __syncthreads();
    float ls = 0.f;
#pragma unroll
    for (int i = 0; i < 8; ++i) { v[i] = expf(v[i] - mx); ls += v[i]; }
    red[tid] = ls; __syncthreads();
    for (int off = 128; off > 0; off >>= 1) {
        if (tid < off) red[tid] += red[tid + off];
        __syncthreads();
    }
    const float inv = 1.f / red[0];
#pragma unroll
    for (int i = 0; i < 8; ++i) attn[b * Sz + i * 256 + tid] = v[i] * inv;
}

// ---------------------------------------------------------------------------
// wsum[b,d] = sum_s attn[b,s]*h_enc[b,s,d]; grid 1024 (64 s-rows per block)
// (round-0 float4 version; the scalar-load rewrite cost ~95us — reverted)
// ---------------------------------------------------------------------------
__global__ __launch_bounds__(256) void wsum_kernel(
    const float* __restrict__ h_enc, const float* __restrict__ attn,
    float* __restrict__ wsum)
{
    __shared__ float aw[64];
    const int b  = blockIdx.x >> 5;
    const int s0 = (blockIdx.x & 31) * 64;
    const int tid = threadIdx.x;
    if (tid < 64) aw[tid] = attn[b * Sz + s0 + tid];
    __syncthreads();
    float4 acc = {0.f, 0.f, 0.f, 0.f};
    const float* base = h_enc + ((size_t)b * Sz + s0) * Dz + tid * 4;
#pragma unroll 4
    for (int s = 0; s < 64; ++s) {
        const float a = aw[s];
        const float4 h = *(const float4*)(base + (size_t)s * Dz);
        acc.x += a * h.x; acc.y += a * h.y; acc.z += a * h.z; acc.w += a * h.w;
    }
    float* o = wsum + b * Dz + tid * 4;
    atomicAdd(o + 0, acc.x); atomicAdd(o + 1, acc.y);
    atomicAdd(o + 2, acc.z); atomicAdd(o + 3, acc.w);
}

// ---------------------------------------------------------------------------
// out_ctx[b,u] += partial wsum[b,:]@W_enc (8 d-chunks, atop b_enc init)
// ---------------------------------------------------------------------------
__global__ __launch_bounds__(256) void ctx_partial_kernel(
    const float* __restrict__ wsum, const float* __restrict__ W_enc,
    float* __restrict__ out_ctx)
{
    __shared__ float hs[128];
    const int b  = blockIdx.x >> 3;
    const int d0 = (blockIdx.x & 7) * 128;
    const int tid = threadIdx.x;
    const int u4 = tid * 4;
    if (tid < 128) hs[tid] = wsum[b * Dz + d0 + tid];
    __syncthreads();
    float4 acc = {0.f, 0.f, 0.f, 0.f};
#pragma unroll 4
    for (int d = 0; d < 128; ++d) {
        const float  a = hs[d];
        const float4 wv = *(const float4*)&W_enc[(size_t)(d0 + d) * Uz + u4];
        acc.x += a * wv.x; acc.y += a * wv.y; acc.z += a * wv.z; acc.w += a * wv.w;
    }
    float* o = out_ctx + b * Uz + u4;
    atomicAdd(o + 0, acc.x); atomicAdd(o + 1, acc.y);
    atomicAdd(o + 2, acc.z); atomicAdd(o + 3, acc.w);
}

// ---------------------------------------------------------------------------
// Fallback fp32 path (only if ws too small for bf16 staging)
// ---------------------------------------------------------------------------
__global__ __launch_bounds__(256) void dec_proj_kernel(
    const float* __restrict__ h_dec, const float* __restrict__ W_dec,
    const float* __restrict__ b_dec, float* __restrict__ dec_p)
{
    __shared__ float hs[Dz];
    const int b = blockIdx.x >> 2;
    const int u = ((blockIdx.x & 3) << 8) + threadIdx.x;
    for (int d = threadIdx.x; d < Dz; d += 256) hs[d] = h_dec[b * Dz + d];
    __syncthreads();
    float acc = 0.f;
#pragma unroll 4
    for (int d = 0; d < Dz; ++d) acc += hs[d] * W_dec[d * Uz + u];
    dec_p[b * Uz + u] = acc + b_dec[u];
}

#define MT 64
#define NT 64
#define KT 64
__global__ __launch_bounds__(256) void score_kernel(
    const float* __restrict__ h_enc, const float* __restrict__ W_enc,
    const float* __restrict__ dec_p, const float* __restrict__ W_com,
    const float* __restrict__ b_com, float* __restrict__ score)
{
    __shared__ __align__(16) float As[KT][MT + 4];
    __shared__ __align__(16) float Bs[KT][NT + 4];
    __shared__ float red[MT][17];
    const int tid = threadIdx.x;
    const int tx = tid & 15;
    const int ty = tid >> 4;
    const int m0 = blockIdx.x * MT;
    const int b  = m0 / Sz;
    float s_acc = 0.f;
    for (int u0 = 0; u0 < Uz; u0 += NT) {
        float acc[4][4];
#pragma unroll
        for (int i = 0; i < 4; ++i)
#pragma unroll
            for (int j = 0; j < 4; ++j) acc[i][j] = 0.f;
        for (int k0 = 0; k0 < Dz; k0 += KT) {
            __syncthreads();
#pragma unroll
            for (int i = 0; i < 4; ++i) {
                const int row = ty + i * 16;
                const int c4  = tx * 4;
                const float4 v = *(const float4*)&h_enc[(size_t)(m0 + row) * Dz + k0 + c4];
                As[c4 + 0][row] = v.x; As[c4 + 1][row] = v.y;
                As[c4 + 2][row] = v.z; As[c4 + 3][row] = v.w;
            }
#pragma unroll
            for (int i = 0; i < 4; ++i) {
                const int row = ty + i * 16;
                *(float4*)&Bs[row][tx * 4] =
                    *(const float4*)&W_enc[(size_t)(k0 + row) * Uz + u0 + tx * 4];
            }
            __syncthreads();
#pragma unroll 8
            for (int k = 0; k < KT; ++k) {
                const float4 a = *(const float4*)&As[k][ty * 4];
                const float4 wv = *(const float4*)&Bs[k][tx * 4];
                acc[0][0] += a.x * wv.x; acc[0][1] += a.x * wv.y; acc[0][2] += a.x * wv.z; acc[0][3] += a.x * wv.w;
                acc[1][0] += a.y * wv.x; acc[1][1] += a.y * wv.y; acc[1][2] += a.y * wv.z; acc[1][3] += a.y * wv.w;
                acc[2][0] += a.z * wv.x; acc[2][1] += a.z * wv.y; acc[2][2] += a.z * wv.z; acc[2][3] += a.z * wv.w;
                acc[3][0] += a.w * wv.x; acc[3][1] += a.w * wv.y; acc[3][2] += a.w * wv.z; acc[3][3] += a.w * wv.w;
            }
        }
        const float4 dp = *(const float4*)&dec_p[b * Uz + u0 + tx * 4];
        const float4 wc = *(const float4*)&W_com[u0 + tx * 4];
#pragma unroll
        for (int i = 0; i < 4; ++i) {
            const float p = tanhf(acc[i][0] + dp.x) * wc.x + tanhf(acc[i][1] + dp.y) * wc.y
                          + tanhf(acc[i][2] + dp.z) * wc.z + tanhf(acc[i][3] + dp.w) * wc.w;
            red[ty * 4 + i][tx] = p;
        }
        __syncthreads();
        if (tid < MT) {
            float t = 0.f;
#pragma unroll
            for (int j = 0; j < 16; ++j) t += red[tid][j];
            s_acc += t;
        }
    }
    if (tid < MT) score[m0 + tid] = s_acc + b_com[0];
}

__global__ __launch_bounds__(256) void ctx_kernel(
    const float* __restrict__ wsum, const float* __restrict__ W_enc,
    const float* __restrict__ b_enc, float* __restrict__ out)
{
    __shared__ float hs[Dz];
    const int b = blockIdx.x >> 2;
    const int u = ((blockIdx.x & 3) << 8) + threadIdx.x;
    for (int d = threadIdx.x; d < Dz; d += 256) hs[d] = wsum[b * Dz + d];
    __syncthreads();
    float acc = 0.f;
#pragma unroll 4
    for (int d = 0; d < Dz; ++d) acc += hs[d] * W_enc[d * Uz + u];
    out[b * Uz + u] = acc + b_enc[u];
}

// ---------------------------------------------------------------------------
extern "C" void kernel_launch(void* const* d_in, const int* in_sizes, int n_in,
                              void* d_out, int out_size, void* d_ws, size_t ws_size,
                              hipStream_t stream)
{
    const float* h_enc = (const float*)d_in[0];
    const float* h_dec = (const float*)d_in[1];
    const float* W_enc = (const float*)d_in[2];
    const float* b_enc = (const float*)d_in[3];
    const float* W_dec = (const float*)d_in[4];
    const float* b_dec = (const float*)d_in[5];
    const float* W_com = (const float*)d_in[6];
    const float* b_com = (const float*)d_in[7];

    float* out_ctx  = (float*)d_out;            // [B,U]
    float* out_attn = out_ctx + Bz * Uz;        // [B,S]

    const size_t HBF_BYTES = (size_t)Mz * Dz * 2;       // 128 MiB
    const size_t WT_BYTES  = (size_t)Uz * Dz * 2;       // 2 MiB
    const size_t SMALL     = (size_t)(Bz*Uz + Bz*Sz + Bz*Dz) * 4;
    const size_t need      = HBF_BYTES + WT_BYTES + SMALL;

    if (ws_size >= need) {
        char* wsb = (char*)d_ws;
        unsigned short* hbf = (unsigned short*)wsb;
        unsigned short* wT  = (unsigned short*)(wsb + HBF_BYTES);
        float* dec_p = (float*)(wsb + HBF_BYTES + WT_BYTES);
        float* score = dec_p + Bz * Uz;
        float* wsum  = score + Bz * Sz;

        prep_kernel<<<CONV_BLOCKS + WT_BLOCKS + DECI_BLOCKS + SINIT_BLOCKS, 256, 0, stream>>>(
            h_enc, hbf, W_enc, wT, b_dec, dec_p, b_com, score);
        dec_partial_kernel<<<Bz * 8, 256, 0, stream>>>(h_dec, W_dec, dec_p);
        score_mfma_kernel<<<(Mz / 256) * (Uz / 256), 512, 0, stream>>>(hbf, wT, dec_p, W_com, score);
        softmax_init_kernel<<<3 * Bz, 256, 0, stream>>>(score, out_attn, b_enc, out_ctx, wsum);
        wsum_kernel<<<Bz * 32, 256, 0, stream>>>(h_enc, out_attn, wsum);
        ctx_partial_kernel<<<Bz * 8, 256, 0, stream>>>(wsum, W_enc, out_ctx);
    } else {
        float* ws    = (float*)d_ws;
        float* dec_p = ws;
        float* score = ws + Bz * Uz;
        float* wsum  = ws + Bz * Uz + Bz * Sz;

        dec_proj_kernel<<<(Bz * Uz) / 256, 256, 0, stream>>>(h_dec, W_dec, b_dec, dec_p);
        score_kernel<<<Mz / MT, 256, 0, stream>>>(h_enc, W_enc, dec_p, W_com, b_com, score);
        softmax_init_kernel<<<3 * Bz, 256, 0, stream>>>(score, out_attn, b_enc, out_ctx, wsum);
        wsum_kernel<<<Bz * 32, 256, 0, stream>>>(h_enc, out_attn, wsum);
        ctx_kernel<<<(Bz * Uz) / 256, 256, 0, stream>>>(wsum, W_enc, b_enc, out_ctx);
    }
}

// Round 5
// 668.451 us; speedup vs baseline: 1.3127x; 1.0549x over previous
//
#include <hip/hip_runtime.h>
#include <math.h>
#include <stdint.h>

#define Bz 32
#define Sz 2048
#define Dz 1024
#define Uz 1024
#define Mz (Bz*Sz)

typedef __attribute__((ext_vector_type(8))) short bf16x8;
typedef __attribute__((ext_vector_type(4))) float f32x4;

__device__ __forceinline__ unsigned short f2bf(float f) {
    union { float f; uint32_t u; } v; v.f = f;
    uint32_t r = v.u + 0x7FFFu + ((v.u >> 16) & 1u);   // RNE
    return (unsigned short)(r >> 16);
}

__device__ __forceinline__ float fast_tanh(float x) {
    float e = __expf(2.f * x);
    return 1.f - 2.f * __builtin_amdgcn_rcpf(e + 1.f);
}

#define GLD16(gsrc, ldst) \
    __builtin_amdgcn_global_load_lds((__attribute__((address_space(1))) void*)(void*)(gsrc), \
        (__attribute__((address_space(3))) void*)(ldst), 16, 0, 0)

#define CONV_BLOCKS 16384   // (Mz*Dz)/(256*16)
#define WT_BLOCKS   256
#define DECI_BLOCKS 32
#define SINIT_BLOCKS 64     // Bz*Sz / (256*4)

// ---------------------------------------------------------------------------
// PREP (fused): h_enc->bf16 | W_enc->wT bf16 | dec_p = b_dec | score = b_com
// ---------------------------------------------------------------------------
__global__ __launch_bounds__(256) void prep_kernel(
    const float* __restrict__ h_enc, unsigned short* __restrict__ hbf,
    const float* __restrict__ W_enc, unsigned short* __restrict__ wT,
    const float* __restrict__ b_dec, float* __restrict__ dec_p,
    const float* __restrict__ b_com, float* __restrict__ score)
{
    __shared__ float tile[64][65];
    const int bid = blockIdx.x;
    const int tid = threadIdx.x;
    if (bid < CONV_BLOCKS) {
        const size_t i = ((size_t)bid * 256 + tid) * 16;
#pragma unroll
        for (int h = 0; h < 2; ++h) {
            const float4 a = *(const float4*)(h_enc + i + h * 8);
            const float4 c = *(const float4*)(h_enc + i + h * 8 + 4);
            union { unsigned short s[8]; uint4 v; } o;
            o.s[0] = f2bf(a.x); o.s[1] = f2bf(a.y); o.s[2] = f2bf(a.z); o.s[3] = f2bf(a.w);
            o.s[4] = f2bf(c.x); o.s[5] = f2bf(c.y); o.s[6] = f2bf(c.z); o.s[7] = f2bf(c.w);
            *(uint4*)(hbf + i + h * 8) = o.v;
        }
    } else if (bid < CONV_BLOCKS + WT_BLOCKS) {
        const int b2 = bid - CONV_BLOCKS;
        const int c  = tid & 63;
        const int r0 = tid >> 6;
        const int u0 = (b2 & 15) * 64;
        const int d0 = (b2 >> 4) * 64;
        for (int r = r0; r < 64; r += 4)
            tile[r][c] = W_enc[(size_t)(d0 + r) * Uz + u0 + c];
        __syncthreads();
        for (int r = r0; r < 64; r += 4)
            wT[(size_t)(u0 + r) * Dz + d0 + c] = f2bf(tile[c][r]);
    } else if (bid < CONV_BLOCKS + WT_BLOCKS + DECI_BLOCKS) {
        const int b3 = bid - (CONV_BLOCKS + WT_BLOCKS);
        const int u4 = tid * 4;
        *(float4*)&dec_p[b3 * Uz + u4] = *(const float4*)&b_dec[u4];
    } else {
        const int b4 = bid - (CONV_BLOCKS + WT_BLOCKS + DECI_BLOCKS);
        const float bc = b_com[0];
        const int i4 = (b4 * 256 + tid) * 4;
        float4 v = {bc, bc, bc, bc};
        *(float4*)&score[i4] = v;
    }
}

// ---------------------------------------------------------------------------
// dec_p[b,u] += partial h_dec[b,:]@W_dec (8 d-chunks, atop b_dec init)
// ---------------------------------------------------------------------------
__global__ __launch_bounds__(256) void dec_partial_kernel(
    const float* __restrict__ h_dec, const float* __restrict__ W_dec,
    float* __restrict__ dec_p)
{
    __shared__ float hs[128];
    const int b  = blockIdx.x >> 3;
    const int d0 = (blockIdx.x & 7) * 128;
    const int tid = threadIdx.x;
    const int u4 = tid * 4;
    if (tid < 128) hs[tid] = h_dec[b * Dz + d0 + tid];
    __syncthreads();
    float4 acc = {0.f, 0.f, 0.f, 0.f};
#pragma unroll 4
    for (int d = 0; d < 128; ++d) {
        const float  a = hs[d];
        const float4 w = *(const float4*)&W_dec[(size_t)(d0 + d) * Uz + u4];
        acc.x += a * w.x; acc.y += a * w.y; acc.z += a * w.z; acc.w += a * w.w;
    }
    float* o = dec_p + b * Uz + u4;
    atomicAdd(o + 0, acc.x); atomicAdd(o + 1, acc.y);
    atomicAdd(o + 2, acc.z); atomicAdd(o + 3, acc.w);
}

// ---------------------------------------------------------------------------
// K2 (hot, MFMA) v6: 256x256 tile, 8 waves, COUNTED-vmcnt half-tile pipeline
// (T3+T4+T5). v5's 2-phase left MfmaUtil at 24% = the once-per-step vmcnt(0)
// drain is serial with compute (m233 stall). Here: half = 32-k-slice of the
// K-tile; 4 physical LDS slots (slot = H mod 4); 3 halves in flight;
// raw s_barrier + s_waitcnt vmcnt(8) (never 0 in steady state) so certified
// loads were issued 3 halves (~96 MFMA) earlier. setprio(1) around MFMA (T5).
// Hazard ledger: writes to slot (H+3)&3 issue only after reads of half H-1
// (same slot) completed (lgkmcnt(0) before H-1's MFMA + trailing barrier);
// reads of half H certified by end-of-(H-1) vmcnt(8)+barrier. Per-wave vmcnt:
// steady outstanding 12, wait 8 ==> oldest half (the one needed) retired.
// Tail: H=29 wait 4, H=30 wait 0. sched_barrier(0) fences per rule #18.
// Fragment-linear LDS units (1KB), GLD16 direct, 0 bank conflicts.
// ---------------------------------------------------------------------------
__global__ __launch_bounds__(512, 2) void score_mfma_kernel(
    const unsigned short* __restrict__ hbf,   // [Mz][Dz] bf16
    const unsigned short* __restrict__ wT,    // [Uz][Dz] bf16
    const float* __restrict__ dec_p,
    const float* __restrict__ W_com,
    float* __restrict__ score)
{
    __shared__ unsigned short LB[4][32][512]; // 4 half-slots x (16 A + 16 B units) x 1KB
    __shared__ float sred[4][256];

    const int tid  = threadIdx.x;
    const int w    = tid >> 6;        // 0..7
    const int lane = tid & 63;
    const int ln   = lane & 15;
    const int q    = lane >> 4;
    const int wm   = w >> 2;          // 0..1  (m-half)
    const int wn   = w & 3;           // 0..3  (n-quarter)

    // XCD-chunked swizzle (bijective: grid 1024 = 8 xcd x 32 mb x 4 ub)
    const int xcd = blockIdx.x & 7;
    const int idx = blockIdx.x >> 3;          // 0..127
    const int mb  = xcd * 32 + (idx >> 2);    // 0..255
    const int m0  = mb * 256;
    const int ub  = (idx & 3) * 256;
    const int b   = m0 / Sz;

    // staging sources: wave w owns A mgroups 2w,2w+1 and B ngroups 2w,2w+1
    const unsigned short* aA0 = hbf + (size_t)(m0 + w * 32 + ln) * Dz + q * 8;
    const unsigned short* aA1 = aA0 + (size_t)16 * Dz;
    const unsigned short* bB0 = wT + (size_t)(ub + w * 32 + ln) * Dz + q * 8;
    const unsigned short* bB1 = bB0 + (size_t)16 * Dz;

    f32x4 acc[8][4];
#pragma unroll
    for (int i = 0; i < 8; ++i)
#pragma unroll
        for (int j = 0; j < 4; ++j) acc[i][j] = (f32x4){0.f, 0.f, 0.f, 0.f};

    // prologue: stage halves 0,1,2 (k-offsets 0,32,64); certify half 0
#pragma unroll
    for (int h = 0; h < 3; ++h) {
        const int K = (h >> 1) * 64 + (h & 1) * 32;
        GLD16(aA0 + K, &LB[h][2 * w][0]);
        GLD16(aA1 + K, &LB[h][2 * w + 1][0]);
        GLD16(bB0 + K, &LB[h][16 + 2 * w][0]);
        GLD16(bB1 + K, &LB[h][16 + 2 * w + 1][0]);
    }
    asm volatile("s_waitcnt vmcnt(8)" ::: "memory");   // halves 1,2 stay in flight
    __builtin_amdgcn_s_barrier();
    __builtin_amdgcn_sched_barrier(0);

    for (int H = 0; H < 32; ++H) {
        const int sl = H & 3;
        const int h3 = H + 3;
        const int s3 = h3 & 3;
        const int K3 = (h3 >> 1) * 64 + (h3 & 1) * 32;
        bf16x8 af[4], bfr[4];

        // ---- phase 0 (m-rows 0..63 of wave's half) ----
#pragma unroll
        for (int i = 0; i < 4; ++i)
            af[i] = *(const bf16x8*)&LB[sl][wm * 8 + i][lane * 8];
#pragma unroll
        for (int j = 0; j < 4; ++j)
            bfr[j] = *(const bf16x8*)&LB[sl][16 + wn * 4 + j][lane * 8];
        if (h3 < 32) {                       // prefetch A pair of half H+3
            GLD16(aA0 + K3, &LB[s3][2 * w][0]);
            GLD16(aA1 + K3, &LB[s3][2 * w + 1][0]);
        }
        __builtin_amdgcn_sched_barrier(0);
        __builtin_amdgcn_s_barrier();
        asm volatile("s_waitcnt lgkmcnt(0)" ::: "memory");
        __builtin_amdgcn_sched_barrier(0);
        __builtin_amdgcn_s_setprio(1);
#pragma unroll
        for (int i = 0; i < 4; ++i)
#pragma unroll
            for (int j = 0; j < 4; ++j)
                acc[i][j] = __builtin_amdgcn_mfma_f32_16x16x32_bf16(
                    af[i], bfr[j], acc[i][j], 0, 0, 0);
        __builtin_amdgcn_s_setprio(0);
        __builtin_amdgcn_sched_barrier(0);
        __builtin_amdgcn_s_barrier();
        __builtin_amdgcn_sched_barrier(0);

        // ---- phase 1 (m-rows 64..127) ----
#pragma unroll
        for (int i = 0; i < 4; ++i)
            af[i] = *(const bf16x8*)&LB[sl][wm * 8 + 4 + i][lane * 8];
        if (h3 < 32) {                       // prefetch B pair of half H+3
            GLD16(bB0 + K3, &LB[s3][16 + 2 * w][0]);
            GLD16(bB1 + K3, &LB[s3][16 + 2 * w + 1][0]);
        }
        // certify half H+1 (its 4 loads are the oldest outstanding)
        if (H < 29)       { asm volatile("s_waitcnt vmcnt(8)" ::: "memory"); }
        else if (H == 29) { asm volatile("s_waitcnt vmcnt(4)" ::: "memory"); }
        else if (H == 30) { asm volatile("s_waitcnt vmcnt(0)" ::: "memory"); }
        __builtin_amdgcn_sched_barrier(0);
        __builtin_amdgcn_s_barrier();
        asm volatile("s_waitcnt lgkmcnt(0)" ::: "memory");
        __builtin_amdgcn_sched_barrier(0);
        __builtin_amdgcn_s_setprio(1);
#pragma unroll
        for (int i = 0; i < 4; ++i)
#pragma unroll
            for (int j = 0; j < 4; ++j)
                acc[4 + i][j] = __builtin_amdgcn_mfma_f32_16x16x32_bf16(
                    af[i], bfr[j], acc[4 + i][j], 0, 0, 0);
        __builtin_amdgcn_s_setprio(0);
        __builtin_amdgcn_sched_barrier(0);
        __builtin_amdgcn_s_barrier();
        __builtin_amdgcn_sched_barrier(0);
    }

    // epilogue: tanh + dot(W_com); reduce over ln-lanes; in-block LDS reduce
    float dpv[4], wcv[4];
#pragma unroll
    for (int j = 0; j < 4; ++j) {
        const int u = ub + wn * 64 + j * 16 + ln;
        dpv[j] = dec_p[b * Uz + u];
        wcv[j] = W_com[u];
    }
    float racc[8][4];
#pragma unroll
    for (int i = 0; i < 8; ++i)
#pragma unroll
        for (int r = 0; r < 4; ++r) {
            float v = 0.f;
#pragma unroll
            for (int j = 0; j < 4; ++j)
                v += fast_tanh(acc[i][j][r] + dpv[j]) * wcv[j];
            racc[i][r] = v;
        }
#pragma unroll
    for (int off = 1; off < 16; off <<= 1)
#pragma unroll
        for (int i = 0; i < 8; ++i)
#pragma unroll
            for (int r = 0; r < 4; ++r)
                racc[i][r] += __shfl_xor(racc[i][r], off, 64);
    if (ln == 0) {
#pragma unroll
        for (int i = 0; i < 8; ++i)
#pragma unroll
            for (int r = 0; r < 4; ++r)
                sred[wn][wm * 128 + i * 16 + q * 4 + r] = racc[i][r];
    }
    __syncthreads();
    if (tid < 256) {
        const float s = sred[0][tid] + sred[1][tid] + sred[2][tid] + sred[3][tid];
        atomicAdd(&score[m0 + tid], s);
    }
}

// ---------------------------------------------------------------------------
// softmax (blocks 0..31) + out_ctx init = b_enc (32..63) + wsum zero (64..95)
// ---------------------------------------------------------------------------
__global__ __launch_bounds__(256) void softmax_init_kernel(
    const float* __restrict__ score, float* __restrict__ attn,
    const float* __restrict__ b_enc, float* __restrict__ out_ctx,
    float* __restrict__ wsum)
{
    __shared__ float red[256];
    const int tid = threadIdx.x;
    if (blockIdx.x >= 2 * Bz) {
        const int b3 = blockIdx.x - 2 * Bz;
        float4 z = {0.f, 0.f, 0.f, 0.f};
        *(float4*)&wsum[b3 * Dz + tid * 4] = z;
        return;
    }
    if (blockIdx.x >= Bz) {
        const int b2 = blockIdx.x - Bz;
        const int u4 = tid * 4;
        *(float4*)&out_ctx[b2 * Uz + u4] = *(const float4*)&b_enc[u4];
        return;
    }
    const int b = blockIdx.x;
    const float* srow = score + b * Sz;
    float v[8];
    float lm = -1e30f;
#pragma unroll
    for (int i = 0; i < 8; ++i) { v[i] = srow[i * 256 + tid]; lm = fmaxf(lm, v[i]); }
    red[tid] = lm; __syncthreads();
    for (int off = 128; off > 0; off >>= 1) {
        if (tid < off) red[tid] = fmaxf(red[tid], red[tid + off]);
        __syncthreads();
    }
    const float mx = red[0];
    __syncthreads();
    float ls = 0.f;
#pragma unroll
    for (int i = 0; i < 8; ++i) { v[i] = expf(v[i] - mx); ls += v[i]; }
    red[tid] = ls; __syncthreads();
    for (int off = 128; off > 0; off >>= 1) {
        if (tid < off) red[tid] += red[tid + off];
        __syncthreads();
    }
    const float inv = 1.f / red[0];
#pragma unroll
    for (int i = 0; i < 8; ++i) attn[b * Sz + i * 256 + tid] = v[i] * inv;
}

// ---------------------------------------------------------------------------
// wsum[b,d] = sum_s attn[b,s]*h_enc[b,s,d]; grid 1024 (64 s-rows per block)
// (round-0 float4 version; the scalar-load rewrite cost ~95us — reverted)
// ---------------------------------------------------------------------------
__global__ __launch_bounds__(256) void wsum_kernel(
    const float* __restrict__ h_enc, const float* __restrict__ attn,
    float* __restrict__ wsum)
{
    __shared__ float aw[64];
    const int b  = blockIdx.x >> 5;
    const int s0 = (blockIdx.x & 31) * 64;
    const int tid = threadIdx.x;
    if (tid < 64) aw[tid] = attn[b * Sz + s0 + tid];
    __syncthreads();
    float4 acc = {0.f, 0.f, 0.f, 0.f};
    const float* base = h_enc + ((size_t)b * Sz + s0) * Dz + tid * 4;
#pragma unroll 4
    for (int s = 0; s < 64; ++s) {
        const float a = aw[s];
        const float4 h = *(const float4*)(base + (size_t)s * Dz);
        acc.x += a * h.x; acc.y += a * h.y; acc.z += a * h.z; acc.w += a * h.w;
    }
    float* o = wsum + b * Dz + tid * 4;
    atomicAdd(o + 0, acc.x); atomicAdd(o + 1, acc.y);
    atomicAdd(o + 2, acc.z); atomicAdd(o + 3, acc.w);
}

// ---------------------------------------------------------------------------
// out_ctx[b,u] += partial wsum[b,:]@W_enc (8 d-chunks, atop b_enc init)
// ---------------------------------------------------------------------------
__global__ __launch_bounds__(256) void ctx_partial_kernel(
    const float* __restrict__ wsum, const float* __restrict__ W_enc,
    float* __restrict__ out_ctx)
{
    __shared__ float hs[128];
    const int b  = blockIdx.x >> 3;
    const int d0 = (blockIdx.x & 7) * 128;
    const int tid = threadIdx.x;
    const int u4 = tid * 4;
    if (tid < 128) hs[tid] = wsum[b * Dz + d0 + tid];
    __syncthreads();
    float4 acc = {0.f, 0.f, 0.f, 0.f};
#pragma unroll 4
    for (int d = 0; d < 128; ++d) {
        const float  a = hs[d];
        const float4 wv = *(const float4*)&W_enc[(size_t)(d0 + d) * Uz + u4];
        acc.x += a * wv.x; acc.y += a * wv.y; acc.z += a * wv.z; acc.w += a * wv.w;
    }
    float* o = out_ctx + b * Uz + u4;
    atomicAdd(o + 0, acc.x); atomicAdd(o + 1, acc.y);
    atomicAdd(o + 2, acc.z); atomicAdd(o + 3, acc.w);
}

// ---------------------------------------------------------------------------
// Fallback fp32 path (only if ws too small for bf16 staging)
// ---------------------------------------------------------------------------
__global__ __launch_bounds__(256) void dec_proj_kernel(
    const float* __restrict__ h_dec, const float* __restrict__ W_dec,
    const float* __restrict__ b_dec, float* __restrict__ dec_p)
{
    __shared__ float hs[Dz];
    const int b = blockIdx.x >> 2;
    const int u = ((blockIdx.x & 3) << 8) + threadIdx.x;
    for (int d = threadIdx.x; d < Dz; d += 256) hs[d] = h_dec[b * Dz + d];
    __syncthreads();
    float acc = 0.f;
#pragma unroll 4
    for (int d = 0; d < Dz; ++d) acc += hs[d] * W_dec[d * Uz + u];
    dec_p[b * Uz + u] = acc + b_dec[u];
}

#define MT 64
#define NT 64
#define KT 64
__global__ __launch_bounds__(256) void score_kernel(
    const float* __restrict__ h_enc, const float* __restrict__ W_enc,
    const float* __restrict__ dec_p, const float* __restrict__ W_com,
    const float* __restrict__ b_com, float* __restrict__ score)
{
    __shared__ __align__(16) float As[KT][MT + 4];
    __shared__ __align__(16) float Bs[KT][NT + 4];
    __shared__ float red[MT][17];
    const int tid = threadIdx.x;
    const int tx = tid & 15;
    const int ty = tid >> 4;
    const int m0 = blockIdx.x * MT;
    const int b  = m0 / Sz;
    float s_acc = 0.f;
    for (int u0 = 0; u0 < Uz; u0 += NT) {
        float acc[4][4];
#pragma unroll
        for (int i = 0; i < 4; ++i)
#pragma unroll
            for (int j = 0; j < 4; ++j) acc[i][j] = 0.f;
        for (int k0 = 0; k0 < Dz; k0 += KT) {
            __syncthreads();
#pragma unroll
            for (int i = 0; i < 4; ++i) {
                const int row = ty + i * 16;
                const int c4  = tx * 4;
                const float4 v = *(const float4*)&h_enc[(size_t)(m0 + row) * Dz + k0 + c4];
                As[c4 + 0][row] = v.x; As[c4 + 1][row] = v.y;
                As[c4 + 2][row] = v.z; As[c4 + 3][row] = v.w;
            }
#pragma unroll
            for (int i = 0; i < 4; ++i) {
                const int row = ty + i * 16;
                *(float4*)&Bs[row][tx * 4] =
                    *(const float4*)&W_enc[(size_t)(k0 + row) * Uz + u0 + tx * 4];
            }
            __syncthreads();
#pragma unroll 8
            for (int k = 0; k < KT; ++k) {
                const float4 a = *(const float4*)&As[k][ty * 4];
                const float4 wv = *(const float4*)&Bs[k][tx * 4];
                acc[0][0] += a.x * wv.x; acc[0][1] += a.x * wv.y; acc[0][2] += a.x * wv.z; acc[0][3] += a.x * wv.w;
                acc[1][0] += a.y * wv.x; acc[1][1] += a.y * wv.y; acc[1][2] += a.y * wv.z; acc[1][3] += a.y * wv.w;
                acc[2][0] += a.z * wv.x; acc[2][1] += a.z * wv.y; acc[2][2] += a.z * wv.z; acc[2][3] += a.z * wv.w;
                acc[3][0] += a.w * wv.x; acc[3][1] += a.w * wv.y; acc[3][2] += a.w * wv.z; acc[3][3] += a.w * wv.w;
            }
        }
        const float4 dp = *(const float4*)&dec_p[b * Uz + u0 + tx * 4];
        const float4 wc = *(const float4*)&W_com[u0 + tx * 4];
#pragma unroll
        for (int i = 0; i < 4; ++i) {
            const float p = tanhf(acc[i][0] + dp.x) * wc.x + tanhf(acc[i][1] + dp.y) * wc.y
                          + tanhf(acc[i][2] + dp.z) * wc.z + tanhf(acc[i][3] + dp.w) * wc.w;
            red[ty * 4 + i][tx] = p;
        }
        __syncthreads();
        if (tid < MT) {
            float t = 0.f;
#pragma unroll
            for (int j = 0; j < 16; ++j) t += red[tid][j];
            s_acc += t;
        }
    }
    if (tid < MT) score[m0 + tid] = s_acc + b_com[0];
}

__global__ __launch_bounds__(256) void ctx_kernel(
    const float* __restrict__ wsum, const float* __restrict__ W_enc,
    const float* __restrict__ b_enc, float* __restrict__ out)
{
    __shared__ float hs[Dz];
    const int b = blockIdx.x >> 2;
    const int u = ((blockIdx.x & 3) << 8) + threadIdx.x;
    for (int d = threadIdx.x; d < Dz; d += 256) hs[d] = wsum[b * Dz + d];
    __syncthreads();
    float acc = 0.f;
#pragma unroll 4
    for (int d = 0; d < Dz; ++d) acc += hs[d] * W_enc[d * Uz + u];
    out[b * Uz + u] = acc + b_enc[u];
}

// ---------------------------------------------------------------------------
extern "C" void kernel_launch(void* const* d_in, const int* in_sizes, int n_in,
                              void* d_out, int out_size, void* d_ws, size_t ws_size,
                              hipStream_t stream)
{
    const float* h_enc = (const float*)d_in[0];
    const float* h_dec = (const float*)d_in[1];
    const float* W_enc = (const float*)d_in[2];
    const float* b_enc = (const float*)d_in[3];
    const float* W_dec = (const float*)d_in[4];
    const float* b_dec = (const float*)d_in[5];
    const float* W_com = (const float*)d_in[6];
    const float* b_com = (const float*)d_in[7];

    float* out_ctx  = (float*)d_out;            // [B,U]
    float* out_attn = out_ctx + Bz * Uz;        // [B,S]

    const size_t HBF_BYTES = (size_t)Mz * Dz * 2;       // 128 MiB
    const size_t WT_BYTES  = (size_t)Uz * Dz * 2;       // 2 MiB
    const size_t SMALL     = (size_t)(Bz*Uz + Bz*Sz + Bz*Dz) * 4;
    const size_t need      = HBF_BYTES + WT_BYTES + SMALL;

    if (ws_size >= need) {
        char* wsb = (char*)d_ws;
        unsigned short* hbf = (unsigned short*)wsb;
        unsigned short* wT  = (unsigned short*)(wsb + HBF_BYTES);
        float* dec_p = (float*)(wsb + HBF_BYTES + WT_BYTES);
        float* score = dec_p + Bz * Uz;
        float* wsum  = score + Bz * Sz;

        prep_kernel<<<CONV_BLOCKS + WT_BLOCKS + DECI_BLOCKS + SINIT_BLOCKS, 256, 0, stream>>>(
            h_enc, hbf, W_enc, wT, b_dec, dec_p, b_com, score);
        dec_partial_kernel<<<Bz * 8, 256, 0, stream>>>(h_dec, W_dec, dec_p);
        score_mfma_kernel<<<(Mz / 256) * (Uz / 256), 512, 0, stream>>>(hbf, wT, dec_p, W_com, score);
        softmax_init_kernel<<<3 * Bz, 256, 0, stream>>>(score, out_attn, b_enc, out_ctx, wsum);
        wsum_kernel<<<Bz * 32, 256, 0, stream>>>(h_enc, out_attn, wsum);
        ctx_partial_kernel<<<Bz * 8, 256, 0, stream>>>(wsum, W_enc, out_ctx);
    } else {
        float* ws    = (float*)d_ws;
        float* dec_p = ws;
        float* score = ws + Bz * Uz;
        float* wsum  = ws + Bz * Uz + Bz * Sz;

        dec_proj_kernel<<<(Bz * Uz) / 256, 256, 0, stream>>>(h_dec, W_dec, b_dec, dec_p);
        score_kernel<<<Mz / MT, 256, 0, stream>>>(h_enc, W_enc, dec_p, W_com, b_com, score);
        softmax_init_kernel<<<3 * Bz, 256, 0, stream>>>(score, out_attn, b_enc, out_ctx, wsum);
        wsum_kernel<<<Bz * 32, 256, 0, stream>>>(h_enc, out_attn, wsum);
        ctx_kernel<<<(Bz * Uz) / 256, 256, 0, stream>>>(wsum, W_enc, b_enc, out_ctx);
    }
}